// Round 17
// baseline (113.706 us; speedup 1.0000x reference)
//
#include <hip/hip_runtime.h>
#include <hip/hip_fp16.h>

// ---------------------------------------------------------------------------
// Wiener 3D patch filter, MI355X — packed-fp16 FFT with VOP3P op_sel/neg
// fused butterflies, packed-f32 spectral middle with FUSED GAINS (single
// inverse channel DFT: B_c = H'0 A0 + u^c H'1 A1 + u^2c H'2 A2), packed-fp16
// epilogue (v_perm lane extraction), fp16 complex LDS, float4 global loads,
// fp16 parity planes, XCD-aware block swizzle.
// 4 patches / 256-thread block; 6 complex planes (half2, row stride 33):
//   plane p (p=0..3): Z_p = fft2(a0_p + i*a1_p)   (later reused for Q_p)
//   plane 4+j (j=0,1): W_j = fft2(a2_{2j} + i*a2_{2j+1})  (reused for R_j)
// Inverse passes: col (ky->y) then row (kx->x); final pass stores 4-px
// packed-half segments (8B) to fp16 parity planes. f32 atomic fallback.
// ---------------------------------------------------------------------------

typedef float v2f __attribute__((ext_vector_type(2)));

constexpr float TWR[16] = {
  1.0f, 0.98078528040323044f, 0.92387953251128674f, 0.83146961230254524f,
  0.70710678118654752f, 0.55557023301960222f, 0.38268343236508977f, 0.19509032201612827f,
  0.0f, -0.19509032201612827f, -0.38268343236508977f, -0.55557023301960222f,
  -0.70710678118654752f, -0.83146961230254524f, -0.92387953251128674f, -0.98078528040323044f
};
constexpr float TWI[16] = {
  -0.0f, -0.19509032201612827f, -0.38268343236508977f, -0.55557023301960222f,
  -0.70710678118654752f, -0.83146961230254524f, -0.92387953251128674f, -0.98078528040323044f,
  -1.0f, -0.98078528040323044f, -0.92387953251128674f, -0.83146961230254524f,
  -0.70710678118654752f, -0.55557023301960222f, -0.38268343236508977f, -0.19509032201612827f
};
constexpr int REV5[32] = {0,16,8,24,4,20,12,28,2,18,10,26,6,22,14,30,
                          1,17,9,25,5,21,13,29,3,19,11,27,7,23,15,31};
// W1C[i] = exp(-(i-15.5)^2 / 76.8)
constexpr float W1C[32] = {
  0.0437942f, 0.0647235f, 0.0931963f, 0.1307451f,
  0.1787074f, 0.2379852f, 0.3087788f, 0.3903331f,
  0.4807436f, 0.5768747f, 0.6744349f, 0.7682257f,
  0.8525655f, 0.9218431f, 0.9711281f, 0.9967501f,
  0.9967501f, 0.9711281f, 0.9218431f, 0.8525655f,
  0.7682257f, 0.6744349f, 0.5768747f, 0.4807436f,
  0.3903331f, 0.3087788f, 0.2379852f, 0.1787074f,
  0.1307451f, 0.0931963f, 0.0647235f, 0.0437942f
};
// MROW[r] = sum_k W1C[r+8k]^2  (separable overlap-add mask row)
constexpr float MROW[8] = {
  1.37890303f, 1.37540769f, 1.36997963f, 1.36606926f,
  1.36606926f, 1.36997963f, 1.37540769f, 1.37890303f
};

constexpr float S3    = 0.86602540378443865f;  // sqrt(3)/2
constexpr float EPSF  = 1e-15f;
constexpr float CS    = 1.1499041e-4f;         // (mean win^2)^2 / 1024
constexpr float INV6144 = 1.0f / 6144.0f;

#define NBLK 4489                // (4*67*67)/4 patches per block = 4
#define PLANE_FLOATS (4 * 3 * 512 * 512)
#define WS_NEEDED    ((size_t)16 * PLANE_FLOATS * 2)   // fp16 planes, 100.7 MB
#define LSTR 33                 // row stride in half2 (= dwords), padded
#define PL   (32 * LSTR)        // complex plane = 1056 half2

// bijective XCD-aware swizzle (m204): XCD k owns a contiguous chunk of blocks
__device__ __forceinline__ int xcd_swizzle(int orig) {
  const int q = NBLK >> 3, r = NBLK & 7;           // 561, 1
  const int xcd = orig & 7, idx = orig >> 3;
  return (xcd < r ? xcd * (q + 1) : r * (q + 1) + (xcd - r) * q) + idx;
}

// ---- VOP3P fused complex helpers (swap/negate via op_sel/neg modifiers) ----
// t = (m.lo - wi*v.hi, m.hi + wi*v.lo)   [wi2 = (wi,wi) broadcast]
__device__ __forceinline__ __half2 pk_fma_cross(__half2 wi2, __half2 v, __half2 m) {
  unsigned d;
  asm("v_pk_fma_f16 %0, %1, %2, %3 op_sel:[0,1,0] op_sel_hi:[1,0,1] neg_lo:[1,0,0] neg_hi:[0,0,0]"
      : "=v"(d)
      : "v"(__builtin_bit_cast(unsigned, wi2)),
        "v"(__builtin_bit_cast(unsigned, v)),
        "v"(__builtin_bit_cast(unsigned, m)));
  return __builtin_bit_cast(__half2, d);
}

// K=8 butterfly (w = -i fwd / +i inv) fused: swap + sign + add in 2 VOP3P ops
template<int SIGN>
__device__ __forceinline__ void bfly_k8(__half2& u, __half2& v) {
  unsigned up, vp;
  const unsigned uu = __builtin_bit_cast(unsigned, u);
  const unsigned vv = __builtin_bit_cast(unsigned, v);
  if constexpr (SIGN < 0) {
    asm("v_pk_add_f16 %0, %2, %3 op_sel:[0,1] op_sel_hi:[1,0] neg_lo:[0,0] neg_hi:[0,1]\n\t"
        "v_pk_add_f16 %1, %2, %3 op_sel:[0,1] op_sel_hi:[1,0] neg_lo:[0,1] neg_hi:[0,0]"
        : "=&v"(up), "=&v"(vp) : "v"(uu), "v"(vv));
  } else {
    asm("v_pk_add_f16 %0, %2, %3 op_sel:[0,1] op_sel_hi:[1,0] neg_lo:[0,1] neg_hi:[0,0]\n\t"
        "v_pk_add_f16 %1, %2, %3 op_sel:[0,1] op_sel_hi:[1,0] neg_lo:[0,0] neg_hi:[0,1]"
        : "=&v"(up), "=&v"(vp) : "v"(uu), "v"(vv));
  }
  u = __builtin_bit_cast(__half2, up);
  v = __builtin_bit_cast(__half2, vp);
}

// ---- packed butterfly with compile-time twiddle specialization ----
template<int SIGN, int K>
__device__ __forceinline__ void bflyh(__half2& u, __half2& v) {
  if constexpr (K == 0) {
    const __half2 t = v;
    v = __hsub2(u, t);
    u = __hadd2(u, t);
  } else if constexpr (K == 8) {
    bfly_k8<SIGN>(u, v);
  } else {
    constexpr float wr = TWR[K];
    constexpr float wi = (SIGN < 0) ? TWI[K] : -TWI[K];
    const __half2 wr2 = __float2half2_rn(wr);
    const __half2 wi2 = __float2half2_rn(wi);
    const __half2 m = __hmul2(wr2, v);         // (wr*vr, wr*vi)
    const __half2 t = pk_fma_cross(wi2, v, m); // (wr*vr - wi*vi, wr*vi + wi*vr)
    const __half2 un = __hadd2(u, t);
    v = __hsub2(u, t);
    u = un;
  }
}

template<int SIGN, int S, int J>
__device__ __forceinline__ void stage_jh(__half2* z) {
  constexpr int m = 1 << S, h = m >> 1, ts = 32 >> S;
  if constexpr (J < h) {
    #pragma unroll
    for (int k = 0; k < 32; k += m)
      bflyh<SIGN, J * ts>(z[k + J], z[k + J + h]);
    stage_jh<SIGN, S, J + 1>(z);
  }
}

template<int SIGN>
__device__ __forceinline__ void fft32h(__half2* z) {
  stage_jh<SIGN, 1, 0>(z);
  stage_jh<SIGN, 2, 0>(z);
  stage_jh<SIGN, 3, 0>(z);
  stage_jh<SIGN, 4, 0>(z);
  stage_jh<SIGN, 5, 0>(z);
}

// reflect-pad index mapping, N=512, mode='reflect'
__device__ __forceinline__ int refl(int v) {
  v = (v < 0) ? -v : v;
  return (v >= 512) ? (1022 - v) : v;
}

__device__ __forceinline__ v2f v2max0(v2f a) {
  return (v2f){fmaxf(a.x, 0.f), fmaxf(a.y, 0.f)};
}

// MODE 0: atomicAdd f32 into out (fallback). MODE 1: fp16 parity-plane store.
template<int MODE>
__global__ __launch_bounds__(256)
void wiener_patch(const float* __restrict__ I,
                  const float* __restrict__ Sd,
                  void* __restrict__ dstv)
{
  __shared__ __half2 sc[6 * PL];   // 25,344 B
  __shared__ float red[24];        // [p*6 + {I0,I1,I2,S0,S1,S2}]
  __shared__ int   pgeo[16];       // [p*4 + {py,px,b,parity}]

  const int t  = threadIdx.x;
  const int q  = t >> 6;           // patch slot 0..3 (wave == patch)
  const int tl = t & 63;

  if (t < 4) {
    int pp = xcd_swizzle(blockIdx.x) * 4 + t;
    int ppx = pp % 67 + 1;  pp /= 67;
    int ppy = pp % 67 + 1;
    int pb  = pp / 67;
    pgeo[t*4+0] = ppy; pgeo[t*4+1] = ppx; pgeo[t*4+2] = pb;
    pgeo[t*4+3] = ((ppy & 3) << 2) | (ppx & 3);
  }
  __syncthreads();

  // ---- load: 64 threads/patch; (a0,a1) -> half2 Z plane, a2 -> b16 W half --
  const int py = pgeo[q*4+0], px = pgeo[q*4+1], b = pgeo[q*4+2];
  {
    float sI0=0.f,sI1=0.f,sI2=0.f,sS0=0.f,sS1=0.f,sS2=0.f;
    const int gy0 = py * 8 - 32, gx0 = px * 8 - 32;
    const size_t bbase = (size_t)b * 3 * 262144;
    const int zb = q * PL;
    const int wb = (4 + (q >> 1)) * PL;
    const int par = q & 1;
    __half* scH = reinterpret_cast<__half*>(sc);

    if (gx0 >= 0 && gx0 <= 480) {
      // interior in x: float4 loads (wave-uniform branch)
      const int c4 = (tl & 7) * 4, r0 = tl >> 3;     // 8 float4-cols x 8 rows
      #pragma unroll
      for (int i = 0; i < 4; ++i) {
        const int y  = r0 + 8 * i;
        const int ry = refl(gy0 + y);
        const size_t g = bbase + (size_t)ry * 512 + gx0 + c4;
        const float4 f0 = *reinterpret_cast<const float4*>(&I[g]);
        const float4 f1 = *reinterpret_cast<const float4*>(&I[g + 262144]);
        const float4 f2 = *reinterpret_cast<const float4*>(&I[g + 524288]);
        const float4 u0 = *reinterpret_cast<const float4*>(&Sd[g]);
        const float4 u1 = *reinterpret_cast<const float4*>(&Sd[g + 262144]);
        const float4 u2 = *reinterpret_cast<const float4*>(&Sd[g + 524288]);
        sI0 += f0.x + f0.y + f0.z + f0.w;
        sI1 += f1.x + f1.y + f1.z + f1.w;
        sI2 += f2.x + f2.y + f2.z + f2.w;
        sS0 += u0.x + u0.y + u0.z + u0.w;
        sS1 += u1.x + u1.y + u1.z + u1.w;
        sS2 += u2.x + u2.y + u2.z + u2.w;
        const int l = y * LSTR + c4;
        sc[zb + l + 0] = __floats2half2_rn(f0.x, f1.x);
        sc[zb + l + 1] = __floats2half2_rn(f0.y, f1.y);
        sc[zb + l + 2] = __floats2half2_rn(f0.z, f1.z);
        sc[zb + l + 3] = __floats2half2_rn(f0.w, f1.w);
        scH[2 * (wb + l + 0) + par] = __float2half_rn(f2.x);
        scH[2 * (wb + l + 1) + par] = __float2half_rn(f2.y);
        scH[2 * (wb + l + 2) + par] = __float2half_rn(f2.z);
        scH[2 * (wb + l + 3) + par] = __float2half_rn(f2.w);
      }
    } else {
      // border in x: scalar reflect path
      const int x  = tl & 31;
      const int y0 = tl >> 5;      // 0/1; rows y0+2i
      const int rx = refl(gx0 + x);
      #pragma unroll
      for (int i = 0; i < 16; ++i) {
        const int y  = y0 + 2 * i;
        const int ry = refl(gy0 + y);
        const size_t g = bbase + (size_t)ry * 512 + rx;
        const float v0 = I[g];            const float u0 = Sd[g];
        const float v1 = I[g + 262144];   const float u1 = Sd[g + 262144];
        const float v2 = I[g + 524288];   const float u2 = Sd[g + 524288];
        sI0 += v0; sI1 += v1; sI2 += v2;
        sS0 += u0; sS1 += u1; sS2 += u2;
        const int l = y * LSTR + x;
        sc[zb + l] = __floats2half2_rn(v0, v1);
        scH[2 * (wb + l) + par] = __float2half_rn(v2);
      }
    }
    #pragma unroll
    for (int off = 32; off > 0; off >>= 1) {
      sI0 += __shfl_down(sI0, off); sI1 += __shfl_down(sI1, off); sI2 += __shfl_down(sI2, off);
      sS0 += __shfl_down(sS0, off); sS1 += __shfl_down(sS1, off); sS2 += __shfl_down(sS2, off);
    }
    if (tl == 0) {                 // wave == patch: direct write, no atomics
      red[q*6+0] = sI0; red[q*6+1] = sI1; red[q*6+2] = sI2;
      red[q*6+3] = sS0; red[q*6+4] = sS1; red[q*6+5] = sS2;
    }
  }
  __syncthreads();

  // ---- pass 1: fwd row FFTs (packed fp16 window + mean-sub) ---------------
  if (t < 192) {
    const int T = t >> 5, row = t & 31;
    float ma, mb;
    if (T < 4) { ma = red[T*6+0] * (1.f/1024.f); mb = red[T*6+1] * (1.f/1024.f); }
    else { const int j = T - 4; ma = red[(2*j)*6+2] * (1.f/1024.f); mb = red[(2*j+1)*6+2] * (1.f/1024.f); }
    const int rb = T * PL + row * LSTR;
    const float hw = 0.5f * W1C[row];
    const __half2 m2 = __floats2half2_rn(ma, mb);
    __half2 z[32];
    #pragma unroll
    for (int i = 0; i < 32; ++i) {
      const int s = REV5[i];
      const __half2 w2 = __float2half2_rn(hw * W1C[s]);
      z[i] = __hmul2(__hsub2(sc[rb + s], m2), w2);
    }
    fft32h<-1>(z);
    #pragma unroll
    for (int i = 0; i < 32; ++i) sc[rb + i] = z[i];
  }
  __syncthreads();

  // ---- pass 2: fwd col FFTs (fully packed) ---------------------------------
  if (t < 192) {
    const int T = t >> 5, col = t & 31;
    const int cb = T * PL + col;
    __half2 z[32];
    #pragma unroll
    for (int i = 0; i < 32; ++i) z[i] = sc[cb + LSTR * REV5[i]];
    fft32h<-1>(z);
    #pragma unroll
    for (int i = 0; i < 32; ++i) sc[cb + LSTR * i] = z[i];
  }
  __syncthreads();

  // ---- spectral middle: packed f32, FUSED gains (single inverse ch-DFT) ----
  for (int task = t; task < 1028; task += 256) {
    const int j = (task >= 514) ? 1 : 0;
    const int u = task - j * 514;
    int ky, kx;
    if (u < 480) { ky = u & 31; kx = 1 + (u >> 5); }
    else { const int e = u - 480; kx = (e >= 17) ? 16 : 0; ky = (e >= 17) ? (e - 17) : e; }
    const int my = (32 - ky) & 31, mx = (32 - kx) & 31;
    const int ok = ky * LSTR + kx, om = my * LSTR + mx;
    const int zp0 = (2 * j) * PL, zp1 = zp0 + PL, wp = (4 + j) * PL;

    const __half2 Wkh = sc[wp + ok], Wmh = sc[wp + om];
    const float Wkr = __low2float(Wkh), Wki = __high2float(Wkh);
    const float Wmr = __low2float(Wmh), Wmi = __high2float(Wmh);
    const __half2 Zk0 = sc[zp0 + ok], Zm0 = sc[zp0 + om];
    const __half2 Zk1 = sc[zp1 + ok], Zm1 = sc[zp1 + om];

    const v2f Zkr = {__low2float(Zk0),  __low2float(Zk1)};
    const v2f Zki = {__high2float(Zk0), __high2float(Zk1)};
    const v2f Zmr = {__low2float(Zm0),  __low2float(Zm1)};
    const v2f Zmi = {__high2float(Zm0), __high2float(Zm1)};

    // Hermitian splits (x2 true scale; 0.5 folded into forward window)
    const v2f F0r = Zkr + Zmr, F0i = Zki - Zmi;
    const v2f F1r = Zki + Zmi, F1i = Zmr - Zkr;
    const v2f F2r = {Wkr + Wmr, Wki + Wmi};
    const v2f F2i = {Wki - Wmi, Wmr - Wkr};
    // forward channel DFT
    const v2f Spr = F1r + F2r, Spi = F1i + F2i, Smr = F1r - F2r, Smi = F1i - F2i;
    const v2f A0r = F0r + Spr,        A0i = F0i + Spi;
    const v2f t1r = F0r - 0.5f * Spr, t1i = F0i - 0.5f * Spi;
    const v2f A1r = t1r + S3 * Smi,   A1i = t1i - S3 * Smr;
    const v2f A2r = t1r - S3 * Smi,   A2i = t1i + S3 * Smr;
    const v2f P0 = A0r * A0r + A0i * A0i + EPSF;
    const v2f P1 = A1r * A1r + A1i * A1i + EPSF;
    const v2f P2 = A2r * A2r + A2i * A2i + EPSF;
    const v2f s0 = {red[(2*j)*6+3], red[(2*j+1)*6+3]};
    const v2f s1 = {red[(2*j)*6+4], red[(2*j+1)*6+4]};
    const v2f s2 = {red[(2*j)*6+5], red[(2*j+1)*6+5]};
    const v2f Pv0 = CS * s0 * s0, Pv1 = CS * s1 * s1, Pv2 = CS * s2 * s2;
    const v2f rp0 = {__builtin_amdgcn_rcpf(P0.x), __builtin_amdgcn_rcpf(P0.y)};
    const v2f rp1 = {__builtin_amdgcn_rcpf(P1.x), __builtin_amdgcn_rcpf(P1.y)};
    const v2f rp2 = {__builtin_amdgcn_rcpf(P2.x), __builtin_amdgcn_rcpf(P2.y)};
    // fused gains: B = sum over k-side + conj(m-side) collapses to ONE
    // inverse channel DFT with H'0=2H0, H'1=H1k+H2m, H'2=H2k+H1m
    // (H1k,H2m share rp1; H2k,H1m share rp2 — Pvv-by-frequency quirk kept)
    const v2f T0 = v2max0(P0 - Pv0);
    const v2f Hh0 = (T0 + T0) * rp0;
    const v2f Hh1 = (v2max0(P1 - Pv1) + v2max0(P1 - Pv2)) * rp1;
    const v2f Hh2 = (v2max0(P2 - Pv2) + v2max0(P2 - Pv1)) * rp2;
    const v2f G0r = Hh0 * A0r, G0i = Hh0 * A0i;
    const v2f G1r = Hh1 * A1r, G1i = Hh1 * A1i;
    const v2f G2r = Hh2 * A2r, G2i = Hh2 * A2i;
    // single inverse channel DFT (u = e^{+2pi i/3})
    const v2f Qpr = G1r + G2r, Qpi = G1i + G2i, Qmr = G1r - G2r, Qmi = G1i - G2i;
    const v2f B0r = G0r + Qpr,        B0i = G0i + Qpi;
    const v2f u1r = G0r - 0.5f * Qpr, u1i = G0i - 0.5f * Qpi;
    const v2f B1r = u1r - S3 * Qmi,   B1i = u1i + S3 * Qmr;
    const v2f B2r = u1r + S3 * Qmi,   B2i = u1i - S3 * Qmr;
    // pack Q = H0 + i*H1 over Z planes (task owns both k and m)
    sc[zp0 + ok] = __floats2half2_rn(B0r.x - B1i.x, B0i.x + B1r.x);
    sc[zp0 + om] = __floats2half2_rn(B0r.x + B1i.x, B1r.x - B0i.x);
    sc[zp1 + ok] = __floats2half2_rn(B0r.y - B1i.y, B0i.y + B1r.y);
    sc[zp1 + om] = __floats2half2_rn(B0r.y + B1i.y, B1r.y - B0i.y);
    // pack R = H2_{p0} + i*H2_{p1} over W plane
    sc[wp + ok] = __floats2half2_rn(B2r.x - B2i.y, B2i.x + B2r.y);
    sc[wp + om] = __floats2half2_rn(B2r.x + B2i.y, B2r.y - B2i.x);
  }
  __syncthreads();

  // ---- pass 3: inv COL FFTs (ky -> y), packed, write back to cols ----------
  if (t < 192) {
    const int T = t >> 5, col = t & 31;
    const int cb = T * PL + col;
    __half2 z[32];
    #pragma unroll
    for (int i = 0; i < 32; ++i) z[i] = sc[cb + LSTR * REV5[i]];
    fft32h<+1>(z);
    #pragma unroll
    for (int i = 0; i < 32; ++i) sc[cb + LSTR * i] = z[i];
  }
  __syncthreads();

  // ---- pass 4: inv ROW FFTs (kx -> x), packed, packed-fp16 epilogue --------
  if (t < 192) {
    const int T = t >> 5, row = t & 31;
    const int rb = T * PL + row * LSTR;
    __half2 z[32];
    #pragma unroll
    for (int i = 0; i < 32; ++i) z[i] = sc[rb + REV5[i]];
    fft32h<+1>(z);

    const float wy = W1C[row];
    const __half2 wy2  = __float2half2_rn(wy);
    const __half2 inv2 = __float2half2_rn(INV6144);

    int pA, cA, pB, cB;
    if (T < 4) { pA = T; cA = 0; pB = T; cB = 1; }
    else { const int j = T - 4; pA = 2*j; cA = 2; pB = 2*j + 1; cB = 2; }

    __half* hdst = reinterpret_cast<__half*>(dstv);
    float*  fdst = reinterpret_cast<float*>(dstv);

    #pragma unroll
    for (int side = 0; side < 2; ++side) {
      const int p = side ? pB : pA;
      const int c = side ? cB : cA;
      const int ppy = pgeo[p*4+0], ppx = pgeo[p*4+1], pb = pgeo[p*4+2];
      const int oy = ppy * 8 - 32 + row;
      if ((unsigned)oy < 512u) {
        const float mc = red[p*6 + c] * (1.f/1024.f);
        const size_t rowbase = (((size_t)pb * 3 + c) * 512 + oy) * 512;
        const size_t pl = (MODE == 1)
            ? (size_t)pgeo[p*4+3] * PLANE_FLOATS + rowbase : rowbase;
        const int ox0 = ppx * 8 - 32;
        if (MODE == 1) {
          const __half2 mc2 = __float2half2_rn(mc);
          const unsigned sel = side ? 0x07060302u : 0x05040100u; // hi/lo pair extract
          #pragma unroll
          for (int k = 0; k < 8; ++k) {
            const int ox = ox0 + 4 * k;
            if ((unsigned)ox < 512u) {   // ox%4==0 -> segment fully in
              __half2 pair[2];
              #pragma unroll
              for (int e2 = 0; e2 < 2; ++e2) {
                const int xx = 4 * k + 2 * e2;
                const unsigned z0 = __builtin_bit_cast(unsigned, z[xx]);
                const unsigned z1 = __builtin_bit_cast(unsigned, z[xx + 1]);
                const __half2 raw2 =
                    __builtin_bit_cast(__half2, __builtin_amdgcn_perm(z1, z0, sel));
                const __half2 wc  = __floats2half2_rn(W1C[xx], W1C[xx + 1]);
                const __half2 wv2 = __hmul2(wy2, wc);
                pair[e2] = __hmul2(__hfma2(raw2, inv2, __hmul2(mc2, wv2)), wv2);
              }
              *reinterpret_cast<float2*>(hdst + pl + ox) =
                  *reinterpret_cast<float2*>(pair);
            }
          }
        } else {
          #pragma unroll
          for (int k = 0; k < 8; ++k) {
            const int ox = ox0 + 4 * k;
            if ((unsigned)ox < 512u) {
              #pragma unroll
              for (int e = 0; e < 4; ++e) {
                const int xx = 4 * k + e;
                const float wv = wy * W1C[xx];
                const float raw = side ? __high2float(z[xx]) : __low2float(z[xx]);
                atomicAdd(fdst + pl + ox + e, (raw * INV6144 + mc * wv) * wv);
              }
            }
          }
        }
      }
    }
  }
}

// MODE1 phase 2: out = (sum of 16 fp16 planes + eps) / (mask + eps); 4 px/thr
__global__ void wiener_combine(const __half* __restrict__ ws, float* __restrict__ out)
{
  const int i4 = (blockIdx.x * 256 + threadIdx.x) * 4;   // out_size = 3,145,728
  float s0 = 0.f, s1 = 0.f, s2 = 0.f, s3 = 0.f;
  #pragma unroll
  for (int p = 0; p < 16; ++p) {
    const float2 r = *reinterpret_cast<const float2*>(ws + (size_t)p * PLANE_FLOATS + i4);
    const __half2* h = reinterpret_cast<const __half2*>(&r);
    s0 += __low2float(h[0]); s1 += __high2float(h[0]);
    s2 += __low2float(h[1]); s3 += __high2float(h[1]);
  }
  const int yy = (i4 >> 9) & 511;
  const float my = MROW[yy & 7];
  float4 o;
  o.x = (s0 + EPSF) / (my * MROW[(i4 + 0) & 7] + EPSF);
  o.y = (s1 + EPSF) / (my * MROW[(i4 + 1) & 7] + EPSF);
  o.z = (s2 + EPSF) / (my * MROW[(i4 + 2) & 7] + EPSF);
  o.w = (s3 + EPSF) / (my * MROW[(i4 + 3) & 7] + EPSF);
  *reinterpret_cast<float4*>(&out[i4]) = o;
}

// MODE0 phase 2: in-place normalize after f32 atomic accumulation
__global__ void wiener_norm(float* __restrict__ out)
{
  const int i = blockIdx.x * 256 + threadIdx.x;
  const int xx = i & 511;
  const int yy = (i >> 9) & 511;
  out[i] = (out[i] + EPSF) / (MROW[yy & 7] * MROW[xx & 7] + EPSF);
}

extern "C" void kernel_launch(void* const* d_in, const int* in_sizes, int n_in,
                              void* d_out, int out_size, void* d_ws, size_t ws_size,
                              hipStream_t stream)
{
  const float* I = (const float*)d_in[0];
  const float* S = (const float*)d_in[1];
  float* out = (float*)d_out;

  if (ws_size >= WS_NEEDED && d_ws != nullptr) {
    // every in-crop plane pixel is written exactly once -> no zeroing needed
    wiener_patch<1><<<dim3(NBLK), dim3(256), 0, stream>>>(I, S, d_ws);
    wiener_combine<<<dim3(out_size / 1024), dim3(256), 0, stream>>>((const __half*)d_ws, out);
  } else {
    hipMemsetAsync(out, 0, (size_t)out_size * sizeof(float), stream);
    wiener_patch<0><<<dim3(NBLK), dim3(256), 0, stream>>>(I, S, d_out);
    wiener_norm<<<dim3(out_size / 256), dim3(256), 0, stream>>>(out);
  }
}

// Round 18
// 107.251 us; speedup vs baseline: 1.0602x; 1.0602x over previous
//
#include <hip/hip_runtime.h>
#include <hip/hip_fp16.h>

// ---------------------------------------------------------------------------
// Wiener 3D patch filter, MI355X — packed-fp16 FFT with VOP3P op_sel/neg
// fused butterflies, packed-f32 spectral middle with FUSED GAINS in an
// unrolled fixed-trip loop (4 independent tasks interleaved for ILP),
// f32 epilogue (r16-verified), fp16 complex LDS, float4 global loads,
// fp16 parity planes, XCD-aware block swizzle.
// 4 patches / 256-thread block; 6 complex planes (half2, row stride 33):
//   plane p (p=0..3): Z_p = fft2(a0_p + i*a1_p)   (later reused for Q_p)
//   plane 4+j (j=0,1): W_j = fft2(a2_{2j} + i*a2_{2j+1})  (reused for R_j)
// Inverse passes: col (ky->y) then row (kx->x); final pass stores 4-px
// packed-half segments (8B) to fp16 parity planes. f32 atomic fallback.
// ---------------------------------------------------------------------------

typedef float v2f __attribute__((ext_vector_type(2)));

constexpr float TWR[16] = {
  1.0f, 0.98078528040323044f, 0.92387953251128674f, 0.83146961230254524f,
  0.70710678118654752f, 0.55557023301960222f, 0.38268343236508977f, 0.19509032201612827f,
  0.0f, -0.19509032201612827f, -0.38268343236508977f, -0.55557023301960222f,
  -0.70710678118654752f, -0.83146961230254524f, -0.92387953251128674f, -0.98078528040323044f
};
constexpr float TWI[16] = {
  -0.0f, -0.19509032201612827f, -0.38268343236508977f, -0.55557023301960222f,
  -0.70710678118654752f, -0.83146961230254524f, -0.92387953251128674f, -0.98078528040323044f,
  -1.0f, -0.98078528040323044f, -0.92387953251128674f, -0.83146961230254524f,
  -0.70710678118654752f, -0.55557023301960222f, -0.38268343236508977f, -0.19509032201612827f
};
constexpr int REV5[32] = {0,16,8,24,4,20,12,28,2,18,10,26,6,22,14,30,
                          1,17,9,25,5,21,13,29,3,19,11,27,7,23,15,31};
// W1C[i] = exp(-(i-15.5)^2 / 76.8)
constexpr float W1C[32] = {
  0.0437942f, 0.0647235f, 0.0931963f, 0.1307451f,
  0.1787074f, 0.2379852f, 0.3087788f, 0.3903331f,
  0.4807436f, 0.5768747f, 0.6744349f, 0.7682257f,
  0.8525655f, 0.9218431f, 0.9711281f, 0.9967501f,
  0.9967501f, 0.9711281f, 0.9218431f, 0.8525655f,
  0.7682257f, 0.6744349f, 0.5768747f, 0.4807436f,
  0.3903331f, 0.3087788f, 0.2379852f, 0.1787074f,
  0.1307451f, 0.0931963f, 0.0647235f, 0.0437942f
};
// MROW[r] = sum_k W1C[r+8k]^2  (separable overlap-add mask row)
constexpr float MROW[8] = {
  1.37890303f, 1.37540769f, 1.36997963f, 1.36606926f,
  1.36606926f, 1.36997963f, 1.37540769f, 1.37890303f
};

constexpr float S3    = 0.86602540378443865f;  // sqrt(3)/2
constexpr float EPSF  = 1e-15f;
constexpr float CS    = 1.1499041e-4f;         // (mean win^2)^2 / 1024
constexpr float INV6144 = 1.0f / 6144.0f;

#define NBLK 4489                // (4*67*67)/4 patches per block = 4
#define PLANE_FLOATS (4 * 3 * 512 * 512)
#define WS_NEEDED    ((size_t)16 * PLANE_FLOATS * 2)   // fp16 planes, 100.7 MB
#define LSTR 33                 // row stride in half2 (= dwords), padded
#define PL   (32 * LSTR)        // complex plane = 1056 half2

// bijective XCD-aware swizzle (m204): XCD k owns a contiguous chunk of blocks
__device__ __forceinline__ int xcd_swizzle(int orig) {
  const int q = NBLK >> 3, r = NBLK & 7;           // 561, 1
  const int xcd = orig & 7, idx = orig >> 3;
  return (xcd < r ? xcd * (q + 1) : r * (q + 1) + (xcd - r) * q) + idx;
}

// ---- VOP3P fused complex helpers (swap/negate via op_sel/neg modifiers) ----
// t = (m.lo - wi*v.hi, m.hi + wi*v.lo)   [wi2 = (wi,wi) broadcast]
__device__ __forceinline__ __half2 pk_fma_cross(__half2 wi2, __half2 v, __half2 m) {
  unsigned d;
  asm("v_pk_fma_f16 %0, %1, %2, %3 op_sel:[0,1,0] op_sel_hi:[1,0,1] neg_lo:[1,0,0] neg_hi:[0,0,0]"
      : "=v"(d)
      : "v"(__builtin_bit_cast(unsigned, wi2)),
        "v"(__builtin_bit_cast(unsigned, v)),
        "v"(__builtin_bit_cast(unsigned, m)));
  return __builtin_bit_cast(__half2, d);
}

// K=8 butterfly (w = -i fwd / +i inv) fused: swap + sign + add in 2 VOP3P ops
template<int SIGN>
__device__ __forceinline__ void bfly_k8(__half2& u, __half2& v) {
  unsigned up, vp;
  const unsigned uu = __builtin_bit_cast(unsigned, u);
  const unsigned vv = __builtin_bit_cast(unsigned, v);
  if constexpr (SIGN < 0) {
    asm("v_pk_add_f16 %0, %2, %3 op_sel:[0,1] op_sel_hi:[1,0] neg_lo:[0,0] neg_hi:[0,1]\n\t"
        "v_pk_add_f16 %1, %2, %3 op_sel:[0,1] op_sel_hi:[1,0] neg_lo:[0,1] neg_hi:[0,0]"
        : "=&v"(up), "=&v"(vp) : "v"(uu), "v"(vv));
  } else {
    asm("v_pk_add_f16 %0, %2, %3 op_sel:[0,1] op_sel_hi:[1,0] neg_lo:[0,1] neg_hi:[0,0]\n\t"
        "v_pk_add_f16 %1, %2, %3 op_sel:[0,1] op_sel_hi:[1,0] neg_lo:[0,0] neg_hi:[0,1]"
        : "=&v"(up), "=&v"(vp) : "v"(uu), "v"(vv));
  }
  u = __builtin_bit_cast(__half2, up);
  v = __builtin_bit_cast(__half2, vp);
}

// ---- packed butterfly with compile-time twiddle specialization ----
template<int SIGN, int K>
__device__ __forceinline__ void bflyh(__half2& u, __half2& v) {
  if constexpr (K == 0) {
    const __half2 t = v;
    v = __hsub2(u, t);
    u = __hadd2(u, t);
  } else if constexpr (K == 8) {
    bfly_k8<SIGN>(u, v);
  } else {
    constexpr float wr = TWR[K];
    constexpr float wi = (SIGN < 0) ? TWI[K] : -TWI[K];
    const __half2 wr2 = __float2half2_rn(wr);
    const __half2 wi2 = __float2half2_rn(wi);
    const __half2 m = __hmul2(wr2, v);         // (wr*vr, wr*vi)
    const __half2 t = pk_fma_cross(wi2, v, m); // (wr*vr - wi*vi, wr*vi + wi*vr)
    const __half2 un = __hadd2(u, t);
    v = __hsub2(u, t);
    u = un;
  }
}

template<int SIGN, int S, int J>
__device__ __forceinline__ void stage_jh(__half2* z) {
  constexpr int m = 1 << S, h = m >> 1, ts = 32 >> S;
  if constexpr (J < h) {
    #pragma unroll
    for (int k = 0; k < 32; k += m)
      bflyh<SIGN, J * ts>(z[k + J], z[k + J + h]);
    stage_jh<SIGN, S, J + 1>(z);
  }
}

template<int SIGN>
__device__ __forceinline__ void fft32h(__half2* z) {
  stage_jh<SIGN, 1, 0>(z);
  stage_jh<SIGN, 2, 0>(z);
  stage_jh<SIGN, 3, 0>(z);
  stage_jh<SIGN, 4, 0>(z);
  stage_jh<SIGN, 5, 0>(z);
}

// reflect-pad index mapping, N=512, mode='reflect'
__device__ __forceinline__ int refl(int v) {
  v = (v < 0) ? -v : v;
  return (v >= 512) ? (1022 - v) : v;
}

__device__ __forceinline__ v2f v2max0(v2f a) {
  return (v2f){fmaxf(a.x, 0.f), fmaxf(a.y, 0.f)};
}

// MODE 0: atomicAdd f32 into out (fallback). MODE 1: fp16 parity-plane store.
template<int MODE>
__global__ __launch_bounds__(256)
void wiener_patch(const float* __restrict__ I,
                  const float* __restrict__ Sd,
                  void* __restrict__ dstv)
{
  __shared__ __half2 sc[6 * PL];   // 25,344 B
  __shared__ float red[24];        // [p*6 + {I0,I1,I2,S0,S1,S2}]
  __shared__ int   pgeo[16];       // [p*4 + {py,px,b,parity}]

  const int t  = threadIdx.x;
  const int q  = t >> 6;           // patch slot 0..3 (wave == patch)
  const int tl = t & 63;

  if (t < 4) {
    int pp = xcd_swizzle(blockIdx.x) * 4 + t;
    int ppx = pp % 67 + 1;  pp /= 67;
    int ppy = pp % 67 + 1;
    int pb  = pp / 67;
    pgeo[t*4+0] = ppy; pgeo[t*4+1] = ppx; pgeo[t*4+2] = pb;
    pgeo[t*4+3] = ((ppy & 3) << 2) | (ppx & 3);
  }
  __syncthreads();

  // ---- load: 64 threads/patch; (a0,a1) -> half2 Z plane, a2 -> b16 W half --
  const int py = pgeo[q*4+0], px = pgeo[q*4+1], b = pgeo[q*4+2];
  {
    float sI0=0.f,sI1=0.f,sI2=0.f,sS0=0.f,sS1=0.f,sS2=0.f;
    const int gy0 = py * 8 - 32, gx0 = px * 8 - 32;
    const size_t bbase = (size_t)b * 3 * 262144;
    const int zb = q * PL;
    const int wb = (4 + (q >> 1)) * PL;
    const int par = q & 1;
    __half* scH = reinterpret_cast<__half*>(sc);

    if (gx0 >= 0 && gx0 <= 480) {
      // interior in x: float4 loads (wave-uniform branch)
      const int c4 = (tl & 7) * 4, r0 = tl >> 3;     // 8 float4-cols x 8 rows
      #pragma unroll
      for (int i = 0; i < 4; ++i) {
        const int y  = r0 + 8 * i;
        const int ry = refl(gy0 + y);
        const size_t g = bbase + (size_t)ry * 512 + gx0 + c4;
        const float4 f0 = *reinterpret_cast<const float4*>(&I[g]);
        const float4 f1 = *reinterpret_cast<const float4*>(&I[g + 262144]);
        const float4 f2 = *reinterpret_cast<const float4*>(&I[g + 524288]);
        const float4 u0 = *reinterpret_cast<const float4*>(&Sd[g]);
        const float4 u1 = *reinterpret_cast<const float4*>(&Sd[g + 262144]);
        const float4 u2 = *reinterpret_cast<const float4*>(&Sd[g + 524288]);
        sI0 += f0.x + f0.y + f0.z + f0.w;
        sI1 += f1.x + f1.y + f1.z + f1.w;
        sI2 += f2.x + f2.y + f2.z + f2.w;
        sS0 += u0.x + u0.y + u0.z + u0.w;
        sS1 += u1.x + u1.y + u1.z + u1.w;
        sS2 += u2.x + u2.y + u2.z + u2.w;
        const int l = y * LSTR + c4;
        sc[zb + l + 0] = __floats2half2_rn(f0.x, f1.x);
        sc[zb + l + 1] = __floats2half2_rn(f0.y, f1.y);
        sc[zb + l + 2] = __floats2half2_rn(f0.z, f1.z);
        sc[zb + l + 3] = __floats2half2_rn(f0.w, f1.w);
        scH[2 * (wb + l + 0) + par] = __float2half_rn(f2.x);
        scH[2 * (wb + l + 1) + par] = __float2half_rn(f2.y);
        scH[2 * (wb + l + 2) + par] = __float2half_rn(f2.z);
        scH[2 * (wb + l + 3) + par] = __float2half_rn(f2.w);
      }
    } else {
      // border in x: scalar reflect path
      const int x  = tl & 31;
      const int y0 = tl >> 5;      // 0/1; rows y0+2i
      const int rx = refl(gx0 + x);
      #pragma unroll
      for (int i = 0; i < 16; ++i) {
        const int y  = y0 + 2 * i;
        const int ry = refl(gy0 + y);
        const size_t g = bbase + (size_t)ry * 512 + rx;
        const float v0 = I[g];            const float u0 = Sd[g];
        const float v1 = I[g + 262144];   const float u1 = Sd[g + 262144];
        const float v2 = I[g + 524288];   const float u2 = Sd[g + 524288];
        sI0 += v0; sI1 += v1; sI2 += v2;
        sS0 += u0; sS1 += u1; sS2 += u2;
        const int l = y * LSTR + x;
        sc[zb + l] = __floats2half2_rn(v0, v1);
        scH[2 * (wb + l) + par] = __float2half_rn(v2);
      }
    }
    #pragma unroll
    for (int off = 32; off > 0; off >>= 1) {
      sI0 += __shfl_down(sI0, off); sI1 += __shfl_down(sI1, off); sI2 += __shfl_down(sI2, off);
      sS0 += __shfl_down(sS0, off); sS1 += __shfl_down(sS1, off); sS2 += __shfl_down(sS2, off);
    }
    if (tl == 0) {                 // wave == patch: direct write, no atomics
      red[q*6+0] = sI0; red[q*6+1] = sI1; red[q*6+2] = sI2;
      red[q*6+3] = sS0; red[q*6+4] = sS1; red[q*6+5] = sS2;
    }
  }
  __syncthreads();

  // ---- pass 1: fwd row FFTs (packed fp16 window + mean-sub) ---------------
  if (t < 192) {
    const int T = t >> 5, row = t & 31;
    float ma, mb;
    if (T < 4) { ma = red[T*6+0] * (1.f/1024.f); mb = red[T*6+1] * (1.f/1024.f); }
    else { const int j = T - 4; ma = red[(2*j)*6+2] * (1.f/1024.f); mb = red[(2*j+1)*6+2] * (1.f/1024.f); }
    const int rb = T * PL + row * LSTR;
    const float hw = 0.5f * W1C[row];
    const __half2 m2 = __floats2half2_rn(ma, mb);
    __half2 z[32];
    #pragma unroll
    for (int i = 0; i < 32; ++i) {
      const int s = REV5[i];
      const __half2 w2 = __float2half2_rn(hw * W1C[s]);
      z[i] = __hmul2(__hsub2(sc[rb + s], m2), w2);
    }
    fft32h<-1>(z);
    #pragma unroll
    for (int i = 0; i < 32; ++i) sc[rb + i] = z[i];
  }
  __syncthreads();

  // ---- pass 2: fwd col FFTs (fully packed) ---------------------------------
  if (t < 192) {
    const int T = t >> 5, col = t & 31;
    const int cb = T * PL + col;
    __half2 z[32];
    #pragma unroll
    for (int i = 0; i < 32; ++i) z[i] = sc[cb + LSTR * REV5[i]];
    fft32h<-1>(z);
    #pragma unroll
    for (int i = 0; i < 32; ++i) sc[cb + LSTR * i] = z[i];
  }
  __syncthreads();

  // ---- spectral middle: packed f32, fused gains, unrolled fixed-trip loop --
  {
    auto middle_task = [&](int task) {
      const int j = (task >= 514) ? 1 : 0;
      const int u = task - j * 514;
      int ky, kx;
      if (u < 480) { ky = u & 31; kx = 1 + (u >> 5); }
      else { const int e = u - 480; kx = (e >= 17) ? 16 : 0; ky = (e >= 17) ? (e - 17) : e; }
      const int my = (32 - ky) & 31, mx = (32 - kx) & 31;
      const int ok = ky * LSTR + kx, om = my * LSTR + mx;
      const int zp0 = (2 * j) * PL, zp1 = zp0 + PL, wp = (4 + j) * PL;

      const __half2 Wkh = sc[wp + ok], Wmh = sc[wp + om];
      const float Wkr = __low2float(Wkh), Wki = __high2float(Wkh);
      const float Wmr = __low2float(Wmh), Wmi = __high2float(Wmh);
      const __half2 Zk0 = sc[zp0 + ok], Zm0 = sc[zp0 + om];
      const __half2 Zk1 = sc[zp1 + ok], Zm1 = sc[zp1 + om];

      const v2f Zkr = {__low2float(Zk0),  __low2float(Zk1)};
      const v2f Zki = {__high2float(Zk0), __high2float(Zk1)};
      const v2f Zmr = {__low2float(Zm0),  __low2float(Zm1)};
      const v2f Zmi = {__high2float(Zm0), __high2float(Zm1)};

      // Hermitian splits (x2 true scale; 0.5 folded into forward window)
      const v2f F0r = Zkr + Zmr, F0i = Zki - Zmi;
      const v2f F1r = Zki + Zmi, F1i = Zmr - Zkr;
      const v2f F2r = {Wkr + Wmr, Wki + Wmi};
      const v2f F2i = {Wki - Wmi, Wmr - Wkr};
      // forward channel DFT
      const v2f Spr = F1r + F2r, Spi = F1i + F2i, Smr = F1r - F2r, Smi = F1i - F2i;
      const v2f A0r = F0r + Spr,        A0i = F0i + Spi;
      const v2f t1r = F0r - 0.5f * Spr, t1i = F0i - 0.5f * Spi;
      const v2f A1r = t1r + S3 * Smi,   A1i = t1i - S3 * Smr;
      const v2f A2r = t1r - S3 * Smi,   A2i = t1i + S3 * Smr;
      const v2f P0 = A0r * A0r + A0i * A0i + EPSF;
      const v2f P1 = A1r * A1r + A1i * A1i + EPSF;
      const v2f P2 = A2r * A2r + A2i * A2i + EPSF;
      const v2f s0 = {red[(2*j)*6+3], red[(2*j+1)*6+3]};
      const v2f s1 = {red[(2*j)*6+4], red[(2*j+1)*6+4]};
      const v2f s2 = {red[(2*j)*6+5], red[(2*j+1)*6+5]};
      const v2f Pv0 = CS * s0 * s0, Pv1 = CS * s1 * s1, Pv2 = CS * s2 * s2;
      const v2f rp0 = {__builtin_amdgcn_rcpf(P0.x), __builtin_amdgcn_rcpf(P0.y)};
      const v2f rp1 = {__builtin_amdgcn_rcpf(P1.x), __builtin_amdgcn_rcpf(P1.y)};
      const v2f rp2 = {__builtin_amdgcn_rcpf(P2.x), __builtin_amdgcn_rcpf(P2.y)};
      // fused gains: k-side + conj(m-side) collapse to ONE inverse channel
      // DFT with H'0=2H0, H'1=H1k+H2m, H'2=H2k+H1m (Pvv-by-frequency quirk
      // kept; H1k,H2m share rp1; H2k,H1m share rp2)
      const v2f T0 = v2max0(P0 - Pv0);
      const v2f Hh0 = (T0 + T0) * rp0;
      const v2f Hh1 = (v2max0(P1 - Pv1) + v2max0(P1 - Pv2)) * rp1;
      const v2f Hh2 = (v2max0(P2 - Pv2) + v2max0(P2 - Pv1)) * rp2;
      const v2f G0r = Hh0 * A0r, G0i = Hh0 * A0i;
      const v2f G1r = Hh1 * A1r, G1i = Hh1 * A1i;
      const v2f G2r = Hh2 * A2r, G2i = Hh2 * A2i;
      // single inverse channel DFT (u = e^{+2pi i/3})
      const v2f Qpr = G1r + G2r, Qpi = G1i + G2i, Qmr = G1r - G2r, Qmi = G1i - G2i;
      const v2f B0r = G0r + Qpr,        B0i = G0i + Qpi;
      const v2f u1r = G0r - 0.5f * Qpr, u1i = G0i - 0.5f * Qpi;
      const v2f B1r = u1r - S3 * Qmi,   B1i = u1i + S3 * Qmr;
      const v2f B2r = u1r + S3 * Qmi,   B2i = u1i - S3 * Qmr;
      // pack Q = H0 + i*H1 over Z planes (task owns both k and m)
      sc[zp0 + ok] = __floats2half2_rn(B0r.x - B1i.x, B0i.x + B1r.x);
      sc[zp0 + om] = __floats2half2_rn(B0r.x + B1i.x, B1r.x - B0i.x);
      sc[zp1 + ok] = __floats2half2_rn(B0r.y - B1i.y, B0i.y + B1r.y);
      sc[zp1 + om] = __floats2half2_rn(B0r.y + B1i.y, B1r.y - B0i.y);
      // pack R = H2_{p0} + i*H2_{p1} over W plane
      sc[wp + ok] = __floats2half2_rn(B2r.x - B2i.y, B2i.x + B2r.y);
      sc[wp + om] = __floats2half2_rn(B2r.x + B2i.y, B2r.y - B2i.x);
    };
    #pragma unroll
    for (int it = 0; it < 4; ++it) middle_task(t + it * 256);  // tasks 0..1023
    if (t < 4) middle_task(1024 + t);                          // tail 1024..1027
  }
  __syncthreads();

  // ---- pass 3: inv COL FFTs (ky -> y), packed, write back to cols ----------
  if (t < 192) {
    const int T = t >> 5, col = t & 31;
    const int cb = T * PL + col;
    __half2 z[32];
    #pragma unroll
    for (int i = 0; i < 32; ++i) z[i] = sc[cb + LSTR * REV5[i]];
    fft32h<+1>(z);
    #pragma unroll
    for (int i = 0; i < 32; ++i) sc[cb + LSTR * i] = z[i];
  }
  __syncthreads();

  // ---- pass 4: inv ROW FFTs (kx -> x), packed, f32 epilogue from regs ------
  if (t < 192) {
    const int T = t >> 5, row = t & 31;
    const int rb = T * PL + row * LSTR;
    __half2 z[32];
    #pragma unroll
    for (int i = 0; i < 32; ++i) z[i] = sc[rb + REV5[i]];
    fft32h<+1>(z);

    const float wy = W1C[row];

    int pA, cA, pB, cB;
    if (T < 4) { pA = T; cA = 0; pB = T; cB = 1; }
    else { const int j = T - 4; pA = 2*j; cA = 2; pB = 2*j + 1; cB = 2; }

    __half* hdst = reinterpret_cast<__half*>(dstv);
    float*  fdst = reinterpret_cast<float*>(dstv);

    #pragma unroll
    for (int side = 0; side < 2; ++side) {
      const int p = side ? pB : pA;
      const int c = side ? cB : cA;
      const int ppy = pgeo[p*4+0], ppx = pgeo[p*4+1], pb = pgeo[p*4+2];
      const int oy = ppy * 8 - 32 + row;
      if ((unsigned)oy < 512u) {
        const float mc = red[p*6 + c] * (1.f/1024.f);
        const size_t rowbase = (((size_t)pb * 3 + c) * 512 + oy) * 512;
        const size_t pl = (MODE == 1)
            ? (size_t)pgeo[p*4+3] * PLANE_FLOATS + rowbase : rowbase;
        const int ox0 = ppx * 8 - 32;
        #pragma unroll
        for (int k = 0; k < 8; ++k) {
          const int ox = ox0 + 4 * k;
          if ((unsigned)ox < 512u) {     // ox%4==0 -> segment fully in
            float v[4];
            #pragma unroll
            for (int e = 0; e < 4; ++e) {
              const int xx = 4 * k + e;
              const float wv = wy * W1C[xx];
              const float raw = side ? __high2float(z[xx]) : __low2float(z[xx]);
              v[e] = (raw * INV6144 + mc * wv) * wv;
            }
            if (MODE == 1) {
              __half2 pair[2];
              pair[0] = __floats2half2_rn(v[0], v[1]);
              pair[1] = __floats2half2_rn(v[2], v[3]);
              *reinterpret_cast<float2*>(hdst + pl + ox) =
                  *reinterpret_cast<float2*>(pair);
            } else {
              atomicAdd(fdst + pl + ox + 0, v[0]);
              atomicAdd(fdst + pl + ox + 1, v[1]);
              atomicAdd(fdst + pl + ox + 2, v[2]);
              atomicAdd(fdst + pl + ox + 3, v[3]);
            }
          }
        }
      }
    }
  }
}

// MODE1 phase 2: out = (sum of 16 fp16 planes + eps) / (mask + eps); 4 px/thr
__global__ void wiener_combine(const __half* __restrict__ ws, float* __restrict__ out)
{
  const int i4 = (blockIdx.x * 256 + threadIdx.x) * 4;   // out_size = 3,145,728
  float s0 = 0.f, s1 = 0.f, s2 = 0.f, s3 = 0.f;
  #pragma unroll
  for (int p = 0; p < 16; ++p) {
    const float2 r = *reinterpret_cast<const float2*>(ws + (size_t)p * PLANE_FLOATS + i4);
    const __half2* h = reinterpret_cast<const __half2*>(&r);
    s0 += __low2float(h[0]); s1 += __high2float(h[0]);
    s2 += __low2float(h[1]); s3 += __high2float(h[1]);
  }
  const int yy = (i4 >> 9) & 511;
  const float my = MROW[yy & 7];
  float4 o;
  o.x = (s0 + EPSF) / (my * MROW[(i4 + 0) & 7] + EPSF);
  o.y = (s1 + EPSF) / (my * MROW[(i4 + 1) & 7] + EPSF);
  o.z = (s2 + EPSF) / (my * MROW[(i4 + 2) & 7] + EPSF);
  o.w = (s3 + EPSF) / (my * MROW[(i4 + 3) & 7] + EPSF);
  *reinterpret_cast<float4*>(&out[i4]) = o;
}

// MODE0 phase 2: in-place normalize after f32 atomic accumulation
__global__ void wiener_norm(float* __restrict__ out)
{
  const int i = blockIdx.x * 256 + threadIdx.x;
  const int xx = i & 511;
  const int yy = (i >> 9) & 511;
  out[i] = (out[i] + EPSF) / (MROW[yy & 7] * MROW[xx & 7] + EPSF);
}

extern "C" void kernel_launch(void* const* d_in, const int* in_sizes, int n_in,
                              void* d_out, int out_size, void* d_ws, size_t ws_size,
                              hipStream_t stream)
{
  const float* I = (const float*)d_in[0];
  const float* S = (const float*)d_in[1];
  float* out = (float*)d_out;

  if (ws_size >= WS_NEEDED && d_ws != nullptr) {
    // every in-crop plane pixel is written exactly once -> no zeroing needed
    wiener_patch<1><<<dim3(NBLK), dim3(256), 0, stream>>>(I, S, d_ws);
    wiener_combine<<<dim3(out_size / 1024), dim3(256), 0, stream>>>((const __half*)d_ws, out);
  } else {
    hipMemsetAsync(out, 0, (size_t)out_size * sizeof(float), stream);
    wiener_patch<0><<<dim3(NBLK), dim3(256), 0, stream>>>(I, S, d_out);
    wiener_norm<<<dim3(out_size / 256), dim3(256), 0, stream>>>(out);
  }
}